// Round 18
// baseline (305.023 us; speedup 1.0000x reference)
//
#include <hip/hip_runtime.h>
#include <hip/hip_bf16.h>

// BoostedCausalAttention: bf16 MFMA pipeline
// B=2 T=2048 D=1024 H=16 DH=64, fp32 in/out, bf16 internal compute.
// R6 589 -> R8 swizzle 475 -> R9 pairing 352.9 -> R15 swapped-QK 309.3 ->
// R17 (verified) 302.2: 128^2 dbuf GEMMs + attn V5b (72.4us each).
// R16 lesson: check blocks/CU x CU-coverage before tile changes.
// DS model v3: hi/lo processes RE-READ the same K/V fragments (16 b128/iter
//   wasted) and ps writes are 32 scalar b16 — both pure DS-pipe cost.
// R18: (a) hoist K/V frag LDS reads out of process() — read once per kvt,
//   feed both tiles (+64 VGPR, 112->~180, still 8 waves/CU); (b) ps writes
//   packed as b64 (uint2, 4/process instead of 16 b16; j-values contiguous).

typedef __bf16 bf16x8 __attribute__((ext_vector_type(8)));
typedef float f32x4 __attribute__((ext_vector_type(4)));

__device__ __forceinline__ unsigned short f2bf(float f) {
  union { __hip_bfloat16 h; unsigned short u; } cv;
  cv.h = __float2bfloat16(f);
  return cv.u;
}

#define GLD16(gp, lp) __builtin_amdgcn_global_load_lds(                      \
    (const __attribute__((address_space(1))) void*)(gp),                     \
    (__attribute__((address_space(3))) void*)(lp), 16, 0, 0)

// ---------------- transpose + cast: fp32 [R][C] -> bf16 [C][R] --------------
__global__ __launch_bounds__(256) void transpose_cast(
    const float* __restrict__ in, __hip_bfloat16* __restrict__ out, int R, int C) {
  __shared__ float t[32][33];
  int bx = blockIdx.x * 32, by = blockIdx.y * 32;
  int tx = threadIdx.x, ty = threadIdx.y;
#pragma unroll
  for (int i = 0; i < 32; i += 8)
    t[ty + i][tx] = in[(size_t)(by + ty + i) * C + bx + tx];
  __syncthreads();
#pragma unroll
  for (int i = 0; i < 32; i += 8)
    out[(size_t)(bx + ty + i) * R + by + tx] = __float2bfloat16(t[tx][ty + i]);
}

// ---------------- cast x -> bf16 (vec4) ------------------------------------
__global__ __launch_bounds__(256) void cast_f32_bf16(
    const float* __restrict__ in, __hip_bfloat16* __restrict__ out) {
  size_t e = ((size_t)blockIdx.x * blockDim.x + threadIdx.x) * 4;
  float4 v = *(const float4*)(in + e);
  ushort4 o;
  o.x = f2bf(v.x); o.y = f2bf(v.y); o.z = f2bf(v.z); o.w = f2bf(v.w);
  *(ushort4*)((unsigned short*)out + e) = o;
}

// --- residb = bf16(x - pred)  (catb pred-half written by attn) --------------
__global__ __launch_bounds__(256) void resid_cast(
    const float* __restrict__ x, const float* __restrict__ pred,
    __hip_bfloat16* __restrict__ residb) {
  size_t e = ((size_t)blockIdx.x * blockDim.x + threadIdx.x) * 4;
  float4 xv = *(const float4*)(x + e);
  float4 pv = *(const float4*)(pred + e);
  ushort4 rb;
  rb.x = f2bf(xv.x - pv.x); rb.y = f2bf(xv.y - pv.y);
  rb.z = f2bf(xv.z - pv.z); rb.w = f2bf(xv.w - pv.w);
  *(ushort4*)((unsigned short*)residb + e) = rb;
}

// ------- bf16 MFMA GEMM, 128x128 tile, BK=32, double-buffered (R13) ---------
template <int EPI>
__global__ __launch_bounds__(256) void gemm_bf16(
    const __hip_bfloat16* __restrict__ A, const __hip_bfloat16* __restrict__ Bt,
    const float* __restrict__ bias, void* __restrict__ outp,
    const float* __restrict__ aux0, const float* __restrict__ aux1,
    int M, int N, int K) {
  __shared__ __hip_bfloat16 As[2][128 * 32];
  __shared__ __hip_bfloat16 Bs[2][128 * 32];
  const int tid = threadIdx.x;
  const int lane = tid & 63, wid = tid >> 6;
  const int wr = wid >> 1, wc = wid & 1;
  const int lr = lane & 15, lk = (lane >> 4) * 8;
  const size_t brow = (size_t)blockIdx.y * 128, bcol = (size_t)blockIdx.x * 128;
  f32x4 acc[4][4] = {};
#pragma unroll
  for (int r = 0; r < 2; ++r) {
    int c = tid + r * 256;
    GLD16(A + (brow + (size_t)(c >> 2)) * K + (c & 3) * 8, As[0] + c * 8);
    GLD16(Bt + (bcol + (size_t)(c >> 2)) * K + (c & 3) * 8, Bs[0] + c * 8);
  }
  __syncthreads();
  int cur = 0;
  for (int k0 = 0; k0 < K; k0 += 32) {
    const int nxt = cur ^ 1;
    if (k0 + 32 < K) {
#pragma unroll
      for (int r = 0; r < 2; ++r) {
        int c = tid + r * 256;
        GLD16(A + (brow + (size_t)(c >> 2)) * K + k0 + 32 + (c & 3) * 8,
              As[nxt] + c * 8);
        GLD16(Bt + (bcol + (size_t)(c >> 2)) * K + k0 + 32 + (c & 3) * 8,
              Bs[nxt] + c * 8);
      }
    }
    bf16x8 a[4], b[4];
#pragma unroll
    for (int m = 0; m < 4; ++m)
      a[m] = *(const bf16x8*)(As[cur] + (wr * 64 + m * 16 + lr) * 32 + lk);
#pragma unroll
    for (int n = 0; n < 4; ++n)
      b[n] = *(const bf16x8*)(Bs[cur] + (wc * 64 + n * 16 + lr) * 32 + lk);
#pragma unroll
    for (int m = 0; m < 4; ++m)
#pragma unroll
      for (int n = 0; n < 4; ++n)
        acc[m][n] = __builtin_amdgcn_mfma_f32_16x16x32_bf16(a[m], b[n], acc[m][n], 0, 0, 0);
    __syncthreads();
    cur = nxt;
  }
  const int r0 = (lane >> 4) * 4, cn = lane & 15;
#pragma unroll
  for (int m = 0; m < 4; ++m)
#pragma unroll
    for (int n = 0; n < 4; ++n) {
      size_t col = bcol + wc * 64 + n * 16 + cn;
      float bv = bias[col];
#pragma unroll
      for (int j = 0; j < 4; ++j) {
        size_t row = brow + wr * 64 + m * 16 + r0 + j;
        float v = acc[m][n][j] + bv;
        if constexpr (EPI == 1) {
          float g = 1.0f / (1.0f + __expf(-v));
          float val = g * aux0[row * N + col] + aux1[row * N + col];
          ((__hip_bfloat16*)outp)[row * N + col] = __float2bfloat16(val);
        } else if constexpr (EPI == 2) {
          ((float*)outp)[row * N + col] = v;
        } else {
          ((__hip_bfloat16*)outp)[row * N + col] = __float2bfloat16(v);
        }
      }
    }
}

// ------- causal flash attention V5c (hoisted frags, b64 ps writes) ----------
// R15/R17-verified structure. K/V fragments read from LDS ONCE per kvt into
// registers, fed to both hi/lo processes (softmax/PV remain sequential —
// not R14's full merge). ps writes packed b64. Dual fp32+bf16 output.
__global__ __launch_bounds__(256) void attn_kernel(
    const __hip_bfloat16* __restrict__ qkv, float* __restrict__ outp,
    __hip_bfloat16* __restrict__ outb, int ob_off) {
  const int b = blockIdx.z, h = blockIdx.y, qtp = blockIdx.x;
  const int qlo = qtp, qhi = 31 - qtp;
  const int q0lo = qlo * 64, q0hi = qhi * 64;
  __shared__ __hip_bfloat16 ks[2][64 * 64];
  __shared__ __hip_bfloat16 vts[2][64 * 64];  // V^T [dh][kv], swizzled
  __shared__ __hip_bfloat16 qps[8192];        // Q_hi|Q_lo staging -> ps_hi|ps_lo
  const int tid = threadIdx.x, lane = tid & 63, w = tid >> 6;
  const int lr = lane & 15, lg = lane >> 4;
  const int sw = lr & 7;
  const size_t rs = 3072;
  const __hip_bfloat16* qbh = qkv + ((size_t)b * 2048 + q0hi) * rs + h * 64;
  const __hip_bfloat16* qbl = qkv + ((size_t)b * 2048 + q0lo) * rs + h * 64;
  const __hip_bfloat16* kb = qkv + (size_t)b * 2048 * rs + 1024 + h * 64;
  const __hip_bfloat16* vb = qkv + (size_t)b * 2048 * rs + 2048 + h * 64;

  const int vrow2 = tid >> 3, vseg = tid & 7;  // V staging: kv pair, dh seg
  float4 vr0, vr1;
#pragma unroll
  for (int r = 0; r < 2; ++r) {
    int c = tid + r * 256, row = c >> 3, p = c & 7;
    GLD16(qbh + (size_t)row * rs + (p ^ (row & 7)) * 8, qps + c * 8);
    GLD16(qbl + (size_t)row * rs + (p ^ (row & 7)) * 8, qps + 4096 + c * 8);
    GLD16(kb + (size_t)row * rs + (p ^ (row & 7)) * 8, ks[0] + c * 8);
  }
  vr0 = *(const float4*)(vb + (size_t)(2 * vrow2) * rs + vseg * 8);
  vr1 = *(const float4*)(vb + (size_t)(2 * vrow2 + 1) * rs + vseg * 8);
  __syncthreads();
  const int qrow = w * 16 + lr;
  const bf16x8 qh0 = *(const bf16x8*)(qps + qrow * 64 + ((lg) ^ (qrow & 7)) * 8);
  const bf16x8 qh1 = *(const bf16x8*)(qps + qrow * 64 + ((4 + lg) ^ (qrow & 7)) * 8);
  const bf16x8 ql0 = *(const bf16x8*)(qps + 4096 + qrow * 64 + ((lg) ^ (qrow & 7)) * 8);
  const bf16x8 ql1 = *(const bf16x8*)(qps + 4096 + qrow * 64 + ((4 + lg) ^ (qrow & 7)) * 8);
  {
    const unsigned short* u0 = (const unsigned short*)&vr0;
    const unsigned short* u1 = (const unsigned short*)&vr1;
#pragma unroll
    for (int i = 0; i < 8; ++i) {
      const int dh = vseg * 8 + i;
      const int phys = (vrow2 >> 2) ^ (dh & 7) ^ ((dh >> 3) & 7);
      unsigned int pk = (unsigned int)u0[i] | ((unsigned int)u1[i] << 16);
      *(unsigned int*)(vts[0] + dh * 64 + phys * 8 + 2 * (vrow2 & 3)) = pk;
    }
  }
  __syncthreads();  // Q frags in regs; qps now free for ps

  __hip_bfloat16* psh = qps + w * 1024;         // wave-private, hi tile
  __hip_bfloat16* psl = qps + 4096 + w * 1024;  // wave-private, lo tile
  float m_hi = -1e30f, l_hi = 0.f, m_lo = -1e30f, l_lo = 0.f;
  f32x4 o_hi[4] = {}, o_lo[4] = {};
  int cur = 0;

  // one q-tile update using pre-loaded K/V fragments kf[8], vf[8]
  auto process = [&](const bf16x8& qa0, const bf16x8& qa1, bool diag,
                     float& m_run, float& l_run, f32x4* o, __hip_bfloat16* psw,
                     const bf16x8* kf, const bf16x8* vf) {
    f32x4 s4[4] = {};
#pragma unroll
    for (int n = 0; n < 4; ++n) {
      s4[n] = __builtin_amdgcn_mfma_f32_16x16x32_bf16(kf[n * 2], qa0, s4[n], 0, 0, 0);
      s4[n] = __builtin_amdgcn_mfma_f32_16x16x32_bf16(kf[n * 2 + 1], qa1, s4[n], 0, 0, 0);
    }
    float p[4][4];
    float mloc = -1e30f;
#pragma unroll
    for (int n = 0; n < 4; ++n)
#pragma unroll
      for (int j = 0; j < 4; ++j) {
        float v = s4[n][j] * 0.125f;
        if (diag && (n * 16 + lg * 4 + j) > (w * 16 + lr)) v = -1e30f;
        p[n][j] = v;
        mloc = fmaxf(mloc, v);
      }
    mloc = fmaxf(mloc, __shfl_xor(mloc, 16));
    mloc = fmaxf(mloc, __shfl_xor(mloc, 32));
    const float mn = fmaxf(m_run, mloc);
    const float sc = __expf(m_run - mn);
    m_run = mn;
    float ls = 0.f;
#pragma unroll
    for (int n = 0; n < 4; ++n)
#pragma unroll
      for (int j = 0; j < 4; ++j) { p[n][j] = __expf(p[n][j] - mn); ls += p[n][j]; }
    ls += __shfl_xor(ls, 16);
    ls += __shfl_xor(ls, 32);
    l_run = l_run * sc + ls;
    float scb[4];
#pragma unroll
    for (int j = 0; j < 4; ++j) scb[j] = __shfl(sc, lg * 4 + j);
#pragma unroll
    for (int n = 0; n < 4; ++n)
#pragma unroll
      for (int j = 0; j < 4; ++j) o[n][j] *= scb[j];
    // ps write: 4x b64 (j-values are k-contiguous)
#pragma unroll
    for (int n = 0; n < 4; ++n) {
      uint2 pk;
      pk.x = (unsigned int)f2bf(p[n][0]) | ((unsigned int)f2bf(p[n][1]) << 16);
      pk.y = (unsigned int)f2bf(p[n][2]) | ((unsigned int)f2bf(p[n][3]) << 16);
      *(uint2*)(&psw[lr * 64 + ((n * 2 + (lg >> 1)) ^ sw) * 8 + (lg & 1) * 4]) = pk;
    }
    bf16x8 pa0 = *(const bf16x8*)(&psw[lr * 64 + ((lg) ^ sw) * 8]);
    bf16x8 pa1 = *(const bf16x8*)(&psw[lr * 64 + ((4 + lg) ^ sw) * 8]);
#pragma unroll
    for (int n = 0; n < 4; ++n) {
      o[n] = __builtin_amdgcn_mfma_f32_16x16x32_bf16(pa0, vf[n * 2], o[n], 0, 0, 0);
      o[n] = __builtin_amdgcn_mfma_f32_16x16x32_bf16(pa1, vf[n * 2 + 1], o[n], 0, 0, 0);
    }
  };

  for (int kvt = 0; kvt <= qhi; ++kvt) {
    const int nxt = cur ^ 1;
    const bool pf = (kvt < qhi);
    if (pf) {
      const int kv1 = (kvt + 1) * 64;
#pragma unroll
      for (int r = 0; r < 2; ++r) {
        int c = tid + r * 256, row = c >> 3, p = c & 7;
        GLD16(kb + (size_t)(kv1 + row) * rs + (p ^ (row & 7)) * 8, ks[nxt] + c * 8);
      }
      vr0 = *(const float4*)(vb + (size_t)(kv1 + 2 * vrow2) * rs + vseg * 8);
      vr1 = *(const float4*)(vb + (size_t)(kv1 + 2 * vrow2 + 1) * rs + vseg * 8);
    }
    // hoisted K/V fragment loads: once per kvt, shared by hi and lo
    bf16x8 kf[8], vf[8];
#pragma unroll
    for (int n = 0; n < 4; ++n) {
      const int kr = n * 16 + lr;
      kf[n * 2]     = *(const bf16x8*)(ks[cur] + kr * 64 + ((lg) ^ sw) * 8);
      kf[n * 2 + 1] = *(const bf16x8*)(ks[cur] + kr * 64 + ((4 + lg) ^ sw) * 8);
      const int vdh = n * 16 + lr;
      const int swv = (vdh & 7) ^ ((vdh >> 3) & 7);
      vf[n * 2]     = *(const bf16x8*)(vts[cur] + vdh * 64 + ((lg) ^ swv) * 8);
      vf[n * 2 + 1] = *(const bf16x8*)(vts[cur] + vdh * 64 + ((4 + lg) ^ swv) * 8);
    }
    process(qh0, qh1, kvt == qhi, m_hi, l_hi, o_hi, psh, kf, vf);
    if (kvt <= qlo) process(ql0, ql1, kvt == qlo, m_lo, l_lo, o_lo, psl, kf, vf);
    if (pf) {
      const unsigned short* u0 = (const unsigned short*)&vr0;
      const unsigned short* u1 = (const unsigned short*)&vr1;
#pragma unroll
      for (int i = 0; i < 8; ++i) {
        const int dh = vseg * 8 + i;
        const int phys = (vrow2 >> 2) ^ (dh & 7) ^ ((dh >> 3) & 7);
        unsigned int pk = (unsigned int)u0[i] | ((unsigned int)u1[i] << 16);
        *(unsigned int*)(vts[nxt] + dh * 64 + phys * 8 + 2 * (vrow2 & 3)) = pk;
      }
    }
    __syncthreads();
    cur = nxt;
  }
  const float linv_h = 1.0f / l_hi, linv_l = 1.0f / l_lo;
#pragma unroll
  for (int j = 0; j < 4; ++j) {
    const float lih = __shfl(linv_h, lg * 4 + j);
    const float lil = __shfl(linv_l, lg * 4 + j);
    size_t rowh = (size_t)b * 2048 + q0hi + w * 16 + lg * 4 + j;
    size_t rowl = (size_t)b * 2048 + q0lo + w * 16 + lg * 4 + j;
#pragma unroll
    for (int n = 0; n < 4; ++n) {
      float vh = o_hi[n][j] * lih, vl = o_lo[n][j] * lil;
      outp[rowh * 1024 + h * 64 + n * 16 + lr] = vh;
      outp[rowl * 1024 + h * 64 + n * 16 + lr] = vl;
      outb[rowh * 2048 + ob_off + h * 64 + n * 16 + lr] = __float2bfloat16(vh);
      outb[rowl * 2048 + ob_off + h * 64 + n * 16 + lr] = __float2bfloat16(vl);
    }
  }
}

extern "C" void kernel_launch(void* const* d_in, const int* in_sizes, int n_in,
                              void* d_out, int out_size, void* d_ws, size_t ws_size,
                              hipStream_t stream) {
  const float* x     = (const float*)d_in[0];
  const float* Wqkv0 = (const float*)d_in[1];
  const float* bqkv0 = (const float*)d_in[2];
  const float* Wqkv1 = (const float*)d_in[3];
  const float* bqkv1 = (const float*)d_in[4];
  const float* Wg    = (const float*)d_in[5];
  const float* bg    = (const float*)d_in[6];
  const float* Wo    = (const float*)d_in[7];
  const float* bo    = (const float*)d_in[8];
  float* out = (float*)d_out;

  char* ws = (char*)d_ws;
  __hip_bfloat16* xb   = (__hip_bfloat16*)(ws);              // 8 MB (x_bf16 -> residb -> preout)
  __hip_bfloat16* qkv  = (__hip_bfloat16*)(ws + 8388608);    // 24 MB (qkv0 then qkv1)
  float*          pred = (float*)(ws + 33554432);            // 16 MB
  float*          corr = (float*)(ws + 50331648);            // 16 MB
  __hip_bfloat16* catb = (__hip_bfloat16*)(ws + 67108864);   // 16 MB [pred | corr] bf16
  __hip_bfloat16* Wt0  = (__hip_bfloat16*)(ws + 83886080);   // 6 MB
  __hip_bfloat16* Wt1  = (__hip_bfloat16*)(ws + 90177536);   // 6 MB
  __hip_bfloat16* Wgt  = (__hip_bfloat16*)(ws + 96468992);   // 4 MB
  __hip_bfloat16* Wot  = (__hip_bfloat16*)(ws + 100663296);  // 2 MB  (total ~98 MB)

  dim3 tb(32, 8);
  transpose_cast<<<dim3(3072 / 32, 1024 / 32), tb, 0, stream>>>(Wqkv0, Wt0, 1024, 3072);
  transpose_cast<<<dim3(3072 / 32, 1024 / 32), tb, 0, stream>>>(Wqkv1, Wt1, 1024, 3072);
  transpose_cast<<<dim3(1024 / 32, 2048 / 32), tb, 0, stream>>>(Wg, Wgt, 2048, 1024);
  transpose_cast<<<dim3(1024 / 32, 1024 / 32), tb, 0, stream>>>(Wo, Wot, 1024, 1024);
  cast_f32_bf16<<<4096, 256, 0, stream>>>(x, xb);

  // qkv0 = x @ Wqkv0 + b  (128^2 dbuf, verified)
  gemm_bf16<0><<<dim3(24, 32), 256, 0, stream>>>(xb, Wt0, bqkv0, (void*)qkv,
                                                 nullptr, nullptr, 4096, 3072, 1024);
  attn_kernel<<<dim3(16, 16, 2), 256, 0, stream>>>(qkv, pred, catb, 0);
  resid_cast<<<4096, 256, 0, stream>>>(x, pred, xb);
  // qkv1 = (x - pred) @ Wqkv1 + b
  gemm_bf16<0><<<dim3(24, 32), 256, 0, stream>>>(xb, Wt1, bqkv1, (void*)qkv,
                                                 nullptr, nullptr, 4096, 3072, 1024);
  attn_kernel<<<dim3(16, 16, 2), 256, 0, stream>>>(qkv, corr, catb, 1024);
  // preout = sigmoid(cat @ Wg + bg) * corr + pred   (into xb)
  gemm_bf16<1><<<dim3(8, 32), 256, 0, stream>>>(catb, Wgt, bg, (void*)xb,
                                                corr, pred, 4096, 1024, 2048);
  // out = preout @ Wo + bo (fp32)
  gemm_bf16<2><<<dim3(8, 32), 256, 0, stream>>>(xb, Wot, bo, (void*)out,
                                                nullptr, nullptr, 4096, 1024, 1024);
}

// Round 19
// 297.381 us; speedup vs baseline: 1.0257x; 1.0257x over previous
//
#include <hip/hip_runtime.h>
#include <hip/hip_bf16.h>

// BoostedCausalAttention: bf16 MFMA pipeline
// B=2 T=2048 D=1024 H=16 DH=64, fp32 in/out, bf16 internal compute.
// R6 589 -> R8 swizzle 475 -> R9 pairing 352.9 -> R15 swapped-QK 309.3 ->
// R17 (verified) 302.2 (attn 72.4). R18 (reverted): frag-hoist+b64-ps
// neutral/worse — at 2 blocks/CU the serial dep chain binds, not DS volume.
// R19: (a) attn = exact R17 body + s_setprio(1/0) around QK/PV MFMA
//   clusters (T5: +4-7% measured in attn-like regimes, m191); epilogue
//   writes ONLY bf16 into catb (fp32 pred/corr buffers eliminated).
//   (b) resid_cast reads pred from catb bf16; gate GEMM aux reads catb bf16
//   (stride 2048). ~48MB less HBM traffic.

typedef __bf16 bf16x8 __attribute__((ext_vector_type(8)));
typedef float f32x4 __attribute__((ext_vector_type(4)));

__device__ __forceinline__ unsigned short f2bf(float f) {
  union { __hip_bfloat16 h; unsigned short u; } cv;
  cv.h = __float2bfloat16(f);
  return cv.u;
}

#define GLD16(gp, lp) __builtin_amdgcn_global_load_lds(                      \
    (const __attribute__((address_space(1))) void*)(gp),                     \
    (__attribute__((address_space(3))) void*)(lp), 16, 0, 0)

// ---------------- transpose + cast: fp32 [R][C] -> bf16 [C][R] --------------
__global__ __launch_bounds__(256) void transpose_cast(
    const float* __restrict__ in, __hip_bfloat16* __restrict__ out, int R, int C) {
  __shared__ float t[32][33];
  int bx = blockIdx.x * 32, by = blockIdx.y * 32;
  int tx = threadIdx.x, ty = threadIdx.y;
#pragma unroll
  for (int i = 0; i < 32; i += 8)
    t[ty + i][tx] = in[(size_t)(by + ty + i) * C + bx + tx];
  __syncthreads();
#pragma unroll
  for (int i = 0; i < 32; i += 8)
    out[(size_t)(bx + ty + i) * R + by + tx] = __float2bfloat16(t[tx][ty + i]);
}

// ---------------- cast x -> bf16 (vec4) ------------------------------------
__global__ __launch_bounds__(256) void cast_f32_bf16(
    const float* __restrict__ in, __hip_bfloat16* __restrict__ out) {
  size_t e = ((size_t)blockIdx.x * blockDim.x + threadIdx.x) * 4;
  float4 v = *(const float4*)(in + e);
  ushort4 o;
  o.x = f2bf(v.x); o.y = f2bf(v.y); o.z = f2bf(v.z); o.w = f2bf(v.w);
  *(ushort4*)((unsigned short*)out + e) = o;
}

// --- residb = bf16(x - pred), pred read from catb bf16 (stride 2048) --------
__global__ __launch_bounds__(256) void resid_cast(
    const float* __restrict__ x, const __hip_bfloat16* __restrict__ catb,
    __hip_bfloat16* __restrict__ residb) {
  size_t e = ((size_t)blockIdx.x * blockDim.x + threadIdx.x) * 4;
  float4 xv = *(const float4*)(x + e);
  size_t row = e >> 10, col = e & 1023;
  ushort4 pb = *(const ushort4*)((const unsigned short*)catb + row * 2048 + col);
  union { unsigned int u; float f; } c0, c1, c2, c3;
  c0.u = (unsigned int)pb.x << 16; c1.u = (unsigned int)pb.y << 16;
  c2.u = (unsigned int)pb.z << 16; c3.u = (unsigned int)pb.w << 16;
  ushort4 rb;
  rb.x = f2bf(xv.x - c0.f); rb.y = f2bf(xv.y - c1.f);
  rb.z = f2bf(xv.z - c2.f); rb.w = f2bf(xv.w - c3.f);
  *(ushort4*)((unsigned short*)residb + e) = rb;
}

// ------- bf16 MFMA GEMM, 128x128 tile, BK=32, double-buffered (R13) ---------
// EPI 0: out bf16 = acc+bias
// EPI 1: out bf16 = sigmoid(acc+bias)*bf16aux0 + bf16aux1 (aux stride 2048)
// EPI 2: out fp32 = acc+bias
template <int EPI>
__global__ __launch_bounds__(256) void gemm_bf16(
    const __hip_bfloat16* __restrict__ A, const __hip_bfloat16* __restrict__ Bt,
    const float* __restrict__ bias, void* __restrict__ outp,
    const __hip_bfloat16* __restrict__ aux0, const __hip_bfloat16* __restrict__ aux1,
    int M, int N, int K) {
  __shared__ __hip_bfloat16 As[2][128 * 32];
  __shared__ __hip_bfloat16 Bs[2][128 * 32];
  const int tid = threadIdx.x;
  const int lane = tid & 63, wid = tid >> 6;
  const int wr = wid >> 1, wc = wid & 1;
  const int lr = lane & 15, lk = (lane >> 4) * 8;
  const size_t brow = (size_t)blockIdx.y * 128, bcol = (size_t)blockIdx.x * 128;
  f32x4 acc[4][4] = {};
#pragma unroll
  for (int r = 0; r < 2; ++r) {
    int c = tid + r * 256;
    GLD16(A + (brow + (size_t)(c >> 2)) * K + (c & 3) * 8, As[0] + c * 8);
    GLD16(Bt + (bcol + (size_t)(c >> 2)) * K + (c & 3) * 8, Bs[0] + c * 8);
  }
  __syncthreads();
  int cur = 0;
  for (int k0 = 0; k0 < K; k0 += 32) {
    const int nxt = cur ^ 1;
    if (k0 + 32 < K) {
#pragma unroll
      for (int r = 0; r < 2; ++r) {
        int c = tid + r * 256;
        GLD16(A + (brow + (size_t)(c >> 2)) * K + k0 + 32 + (c & 3) * 8,
              As[nxt] + c * 8);
        GLD16(Bt + (bcol + (size_t)(c >> 2)) * K + k0 + 32 + (c & 3) * 8,
              Bs[nxt] + c * 8);
      }
    }
    bf16x8 a[4], b[4];
#pragma unroll
    for (int m = 0; m < 4; ++m)
      a[m] = *(const bf16x8*)(As[cur] + (wr * 64 + m * 16 + lr) * 32 + lk);
#pragma unroll
    for (int n = 0; n < 4; ++n)
      b[n] = *(const bf16x8*)(Bs[cur] + (wc * 64 + n * 16 + lr) * 32 + lk);
#pragma unroll
    for (int m = 0; m < 4; ++m)
#pragma unroll
      for (int n = 0; n < 4; ++n)
        acc[m][n] = __builtin_amdgcn_mfma_f32_16x16x32_bf16(a[m], b[n], acc[m][n], 0, 0, 0);
    __syncthreads();
    cur = nxt;
  }
  const int r0 = (lane >> 4) * 4, cn = lane & 15;
#pragma unroll
  for (int m = 0; m < 4; ++m)
#pragma unroll
    for (int n = 0; n < 4; ++n) {
      size_t col = bcol + wc * 64 + n * 16 + cn;
      float bv = bias[col];
#pragma unroll
      for (int j = 0; j < 4; ++j) {
        size_t row = brow + wr * 64 + m * 16 + r0 + j;
        float v = acc[m][n][j] + bv;
        if constexpr (EPI == 1) {
          float g = 1.0f / (1.0f + __expf(-v));
          float a0 = __bfloat162float(aux0[row * 2048 + col]);
          float a1 = __bfloat162float(aux1[row * 2048 + col]);
          ((__hip_bfloat16*)outp)[row * N + col] = __float2bfloat16(g * a0 + a1);
        } else if constexpr (EPI == 2) {
          ((float*)outp)[row * N + col] = v;
        } else {
          ((__hip_bfloat16*)outp)[row * N + col] = __float2bfloat16(v);
        }
      }
    }
}

// ------- causal flash attention V5d (R17 body + setprio, bf16-only out) -----
// R15/R17-verified structure. s_setprio(1) around QK and PV MFMA clusters
// (T5). Epilogue writes only bf16 into catb (stride 2048, +ob_off).
__global__ __launch_bounds__(256) void attn_kernel(
    const __hip_bfloat16* __restrict__ qkv,
    __hip_bfloat16* __restrict__ outb, int ob_off) {
  const int b = blockIdx.z, h = blockIdx.y, qtp = blockIdx.x;
  const int qlo = qtp, qhi = 31 - qtp;
  const int q0lo = qlo * 64, q0hi = qhi * 64;
  __shared__ __hip_bfloat16 ks[2][64 * 64];
  __shared__ __hip_bfloat16 vts[2][64 * 64];  // V^T [dh][kv], swizzled
  __shared__ __hip_bfloat16 qps[8192];        // Q_hi|Q_lo staging -> ps_hi|ps_lo
  const int tid = threadIdx.x, lane = tid & 63, w = tid >> 6;
  const int lr = lane & 15, lg = lane >> 4;
  const int sw = lr & 7;
  const size_t rs = 3072;
  const __hip_bfloat16* qbh = qkv + ((size_t)b * 2048 + q0hi) * rs + h * 64;
  const __hip_bfloat16* qbl = qkv + ((size_t)b * 2048 + q0lo) * rs + h * 64;
  const __hip_bfloat16* kb = qkv + (size_t)b * 2048 * rs + 1024 + h * 64;
  const __hip_bfloat16* vb = qkv + (size_t)b * 2048 * rs + 2048 + h * 64;

  const int vrow2 = tid >> 3, vseg = tid & 7;
  float4 vr0, vr1;
#pragma unroll
  for (int r = 0; r < 2; ++r) {
    int c = tid + r * 256, row = c >> 3, p = c & 7;
    GLD16(qbh + (size_t)row * rs + (p ^ (row & 7)) * 8, qps + c * 8);
    GLD16(qbl + (size_t)row * rs + (p ^ (row & 7)) * 8, qps + 4096 + c * 8);
    GLD16(kb + (size_t)row * rs + (p ^ (row & 7)) * 8, ks[0] + c * 8);
  }
  vr0 = *(const float4*)(vb + (size_t)(2 * vrow2) * rs + vseg * 8);
  vr1 = *(const float4*)(vb + (size_t)(2 * vrow2 + 1) * rs + vseg * 8);
  __syncthreads();
  const int qrow = w * 16 + lr;
  const bf16x8 qh0 = *(const bf16x8*)(qps + qrow * 64 + ((lg) ^ (qrow & 7)) * 8);
  const bf16x8 qh1 = *(const bf16x8*)(qps + qrow * 64 + ((4 + lg) ^ (qrow & 7)) * 8);
  const bf16x8 ql0 = *(const bf16x8*)(qps + 4096 + qrow * 64 + ((lg) ^ (qrow & 7)) * 8);
  const bf16x8 ql1 = *(const bf16x8*)(qps + 4096 + qrow * 64 + ((4 + lg) ^ (qrow & 7)) * 8);
  {
    const unsigned short* u0 = (const unsigned short*)&vr0;
    const unsigned short* u1 = (const unsigned short*)&vr1;
#pragma unroll
    for (int i = 0; i < 8; ++i) {
      const int dh = vseg * 8 + i;
      const int phys = (vrow2 >> 2) ^ (dh & 7) ^ ((dh >> 3) & 7);
      unsigned int pk = (unsigned int)u0[i] | ((unsigned int)u1[i] << 16);
      *(unsigned int*)(vts[0] + dh * 64 + phys * 8 + 2 * (vrow2 & 3)) = pk;
    }
  }
  __syncthreads();  // Q frags in regs; qps now free for ps

  __hip_bfloat16* psh = qps + w * 1024;
  __hip_bfloat16* psl = qps + 4096 + w * 1024;
  float m_hi = -1e30f, l_hi = 0.f, m_lo = -1e30f, l_lo = 0.f;
  f32x4 o_hi[4] = {}, o_lo[4] = {};
  int cur = 0;

  auto process = [&](const bf16x8& qa0, const bf16x8& qa1, bool diag,
                     float& m_run, float& l_run, f32x4* o, __hip_bfloat16* psw) {
    f32x4 s4[4] = {};
    __builtin_amdgcn_s_setprio(1);
#pragma unroll
    for (int n = 0; n < 4; ++n) {
      const int kr = n * 16 + lr;
      bf16x8 k0f = *(const bf16x8*)(ks[cur] + kr * 64 + ((lg) ^ sw) * 8);
      bf16x8 k1f = *(const bf16x8*)(ks[cur] + kr * 64 + ((4 + lg) ^ sw) * 8);
      s4[n] = __builtin_amdgcn_mfma_f32_16x16x32_bf16(k0f, qa0, s4[n], 0, 0, 0);
      s4[n] = __builtin_amdgcn_mfma_f32_16x16x32_bf16(k1f, qa1, s4[n], 0, 0, 0);
    }
    __builtin_amdgcn_s_setprio(0);
    float p[4][4];
    float mloc = -1e30f;
#pragma unroll
    for (int n = 0; n < 4; ++n)
#pragma unroll
      for (int j = 0; j < 4; ++j) {
        float v = s4[n][j] * 0.125f;
        if (diag && (n * 16 + lg * 4 + j) > (w * 16 + lr)) v = -1e30f;
        p[n][j] = v;
        mloc = fmaxf(mloc, v);
      }
    mloc = fmaxf(mloc, __shfl_xor(mloc, 16));
    mloc = fmaxf(mloc, __shfl_xor(mloc, 32));
    const float mn = fmaxf(m_run, mloc);
    const float sc = __expf(m_run - mn);
    m_run = mn;
    float ls = 0.f;
#pragma unroll
    for (int n = 0; n < 4; ++n)
#pragma unroll
      for (int j = 0; j < 4; ++j) { p[n][j] = __expf(p[n][j] - mn); ls += p[n][j]; }
    ls += __shfl_xor(ls, 16);
    ls += __shfl_xor(ls, 32);
    l_run = l_run * sc + ls;
    float scb[4];
#pragma unroll
    for (int j = 0; j < 4; ++j) scb[j] = __shfl(sc, lg * 4 + j);
#pragma unroll
    for (int n = 0; n < 4; ++n)
#pragma unroll
      for (int j = 0; j < 4; ++j) o[n][j] *= scb[j];
#pragma unroll
    for (int n = 0; n < 4; ++n)
#pragma unroll
      for (int j = 0; j < 4; ++j)
        psw[lr * 64 + ((n * 2 + (lg >> 1)) ^ sw) * 8 + (lg & 1) * 4 + j] =
            __float2bfloat16(p[n][j]);
    bf16x8 pa0 = *(const bf16x8*)(&psw[lr * 64 + ((lg) ^ sw) * 8]);
    bf16x8 pa1 = *(const bf16x8*)(&psw[lr * 64 + ((4 + lg) ^ sw) * 8]);
    __builtin_amdgcn_s_setprio(1);
#pragma unroll
    for (int n = 0; n < 4; ++n) {
      const int vdh = n * 16 + lr;
      const int swv = (vdh & 7) ^ ((vdh >> 3) & 7);
      bf16x8 v0f = *(const bf16x8*)(vts[cur] + vdh * 64 + ((lg) ^ swv) * 8);
      bf16x8 v1f = *(const bf16x8*)(vts[cur] + vdh * 64 + ((4 + lg) ^ swv) * 8);
      o[n] = __builtin_amdgcn_mfma_f32_16x16x32_bf16(pa0, v0f, o[n], 0, 0, 0);
      o[n] = __builtin_amdgcn_mfma_f32_16x16x32_bf16(pa1, v1f, o[n], 0, 0, 0);
    }
    __builtin_amdgcn_s_setprio(0);
  };

  for (int kvt = 0; kvt <= qhi; ++kvt) {
    const int nxt = cur ^ 1;
    const bool pf = (kvt < qhi);
    if (pf) {
      const int kv1 = (kvt + 1) * 64;
#pragma unroll
      for (int r = 0; r < 2; ++r) {
        int c = tid + r * 256, row = c >> 3, p = c & 7;
        GLD16(kb + (size_t)(kv1 + row) * rs + (p ^ (row & 7)) * 8, ks[nxt] + c * 8);
      }
      vr0 = *(const float4*)(vb + (size_t)(kv1 + 2 * vrow2) * rs + vseg * 8);
      vr1 = *(const float4*)(vb + (size_t)(kv1 + 2 * vrow2 + 1) * rs + vseg * 8);
    }
    process(qh0, qh1, kvt == qhi, m_hi, l_hi, o_hi, psh);
    if (kvt <= qlo) process(ql0, ql1, kvt == qlo, m_lo, l_lo, o_lo, psl);
    if (pf) {
      const unsigned short* u0 = (const unsigned short*)&vr0;
      const unsigned short* u1 = (const unsigned short*)&vr1;
#pragma unroll
      for (int i = 0; i < 8; ++i) {
        const int dh = vseg * 8 + i;
        const int phys = (vrow2 >> 2) ^ (dh & 7) ^ ((dh >> 3) & 7);
        unsigned int pk = (unsigned int)u0[i] | ((unsigned int)u1[i] << 16);
        *(unsigned int*)(vts[nxt] + dh * 64 + phys * 8 + 2 * (vrow2 & 3)) = pk;
      }
    }
    __syncthreads();
    cur = nxt;
  }
  const float linv_h = 1.0f / l_hi, linv_l = 1.0f / l_lo;
#pragma unroll
  for (int j = 0; j < 4; ++j) {
    const float lih = __shfl(linv_h, lg * 4 + j);
    const float lil = __shfl(linv_l, lg * 4 + j);
    size_t rowh = (size_t)b * 2048 + q0hi + w * 16 + lg * 4 + j;
    size_t rowl = (size_t)b * 2048 + q0lo + w * 16 + lg * 4 + j;
#pragma unroll
    for (int n = 0; n < 4; ++n) {
      outb[rowh * 2048 + ob_off + h * 64 + n * 16 + lr] = __float2bfloat16(o_hi[n][j] * lih);
      outb[rowl * 2048 + ob_off + h * 64 + n * 16 + lr] = __float2bfloat16(o_lo[n][j] * lil);
    }
  }
}

extern "C" void kernel_launch(void* const* d_in, const int* in_sizes, int n_in,
                              void* d_out, int out_size, void* d_ws, size_t ws_size,
                              hipStream_t stream) {
  const float* x     = (const float*)d_in[0];
  const float* Wqkv0 = (const float*)d_in[1];
  const float* bqkv0 = (const float*)d_in[2];
  const float* Wqkv1 = (const float*)d_in[3];
  const float* bqkv1 = (const float*)d_in[4];
  const float* Wg    = (const float*)d_in[5];
  const float* bg    = (const float*)d_in[6];
  const float* Wo    = (const float*)d_in[7];
  const float* bo    = (const float*)d_in[8];
  float* out = (float*)d_out;

  char* ws = (char*)d_ws;
  __hip_bfloat16* xb   = (__hip_bfloat16*)(ws);              // 8 MB (x_bf16 -> residb -> preout)
  __hip_bfloat16* qkv  = (__hip_bfloat16*)(ws + 8388608);    // 24 MB (qkv0 then qkv1)
  __hip_bfloat16* catb = (__hip_bfloat16*)(ws + 67108864);   // 16 MB [pred | corr] bf16
  __hip_bfloat16* Wt0  = (__hip_bfloat16*)(ws + 83886080);   // 6 MB
  __hip_bfloat16* Wt1  = (__hip_bfloat16*)(ws + 90177536);   // 6 MB
  __hip_bfloat16* Wgt  = (__hip_bfloat16*)(ws + 96468992);   // 4 MB
  __hip_bfloat16* Wot  = (__hip_bfloat16*)(ws + 100663296);  // 2 MB

  dim3 tb(32, 8);
  transpose_cast<<<dim3(3072 / 32, 1024 / 32), tb, 0, stream>>>(Wqkv0, Wt0, 1024, 3072);
  transpose_cast<<<dim3(3072 / 32, 1024 / 32), tb, 0, stream>>>(Wqkv1, Wt1, 1024, 3072);
  transpose_cast<<<dim3(1024 / 32, 2048 / 32), tb, 0, stream>>>(Wg, Wgt, 2048, 1024);
  transpose_cast<<<dim3(1024 / 32, 1024 / 32), tb, 0, stream>>>(Wo, Wot, 1024, 1024);
  cast_f32_bf16<<<4096, 256, 0, stream>>>(x, xb);

  // qkv0 = x @ Wqkv0 + b  (128^2 dbuf, verified)
  gemm_bf16<0><<<dim3(24, 32), 256, 0, stream>>>(xb, Wt0, bqkv0, (void*)qkv,
                                                 nullptr, nullptr, 4096, 3072, 1024);
  attn_kernel<<<dim3(16, 16, 2), 256, 0, stream>>>(qkv, catb, 0);
  resid_cast<<<4096, 256, 0, stream>>>(x, catb, xb);
  // qkv1 = (x - pred) @ Wqkv1 + b
  gemm_bf16<0><<<dim3(24, 32), 256, 0, stream>>>(xb, Wt1, bqkv1, (void*)qkv,
                                                 nullptr, nullptr, 4096, 3072, 1024);
  attn_kernel<<<dim3(16, 16, 2), 256, 0, stream>>>(qkv, catb, 1024);
  // preout = sigmoid(cat @ Wg + bg) * corr + pred   (into xb, aux from catb)
  gemm_bf16<1><<<dim3(8, 32), 256, 0, stream>>>(catb, Wgt, bg, (void*)xb,
                                                catb + 1024, catb, 4096, 1024, 2048);
  // out = preout @ Wo + bo (fp32)
  gemm_bf16<2><<<dim3(8, 32), 256, 0, stream>>>(xb, Wot, bo, (void*)out,
                                                nullptr, nullptr, 4096, 1024, 1024);
}

// Round 21
// 287.014 us; speedup vs baseline: 1.0627x; 1.0361x over previous
//
#include <hip/hip_runtime.h>
#include <hip/hip_bf16.h>

// BoostedCausalAttention: bf16 MFMA pipeline
// B=2 T=2048 D=1024 H=16 DH=64, fp32 in/out, bf16 internal compute.
// R6 589 -> R8 swizzle 475 -> R9 pairing 352.9 -> R15 swapped-QK 309.3 ->
// R17 302.2 -> R19 (verified) 297.4 (attn 70.1: setprio + bf16-only out).
// Attn is chain/latency-bound at grid-fixed 2 blocks/CU; stop shaving it.
// R20: (1) all prep (4 transposes + x-cast) batched into ONE dispatch
//   (flat 13312-block grid, job by blockIdx range) — kills 4 launch gaps.
//   (2) resid_cast fused into attn0 epilogue (block owns pred slice in regs;
//   reads x fp32, writes residb bf16). (3) T13 defer-max: skip o/l rescale
//   when __all(mloc - m_run <= 8) — exact math, P bounded by e^8.
// R21: identical resubmit (infra UnresponsiveContainer; offline audit clean:
//   prep decode ranges, fused-resid ordering/coverage, T13 scale consistency).

typedef __bf16 bf16x8 __attribute__((ext_vector_type(8)));
typedef float f32x4 __attribute__((ext_vector_type(4)));

__device__ __forceinline__ unsigned short f2bf(float f) {
  union { __hip_bfloat16 h; unsigned short u; } cv;
  cv.h = __float2bfloat16(f);
  return cv.u;
}

#define GLD16(gp, lp) __builtin_amdgcn_global_load_lds(                      \
    (const __attribute__((address_space(1))) void*)(gp),                     \
    (__attribute__((address_space(3))) void*)(lp), 16, 0, 0)

// ---- batched prep: 4x transpose_cast + x cast in one dispatch --------------
// blocks [0,3072) W0 -> Wt0; [3072,6144) W1 -> Wt1; [6144,8192) Wg -> Wgt;
// [8192,9216) Wo -> Wot; [9216,13312) cast x -> xb (1024 elems/block).
__global__ __launch_bounds__(256) void prep_batch(
    const float* __restrict__ W0, __hip_bfloat16* __restrict__ Wt0,
    const float* __restrict__ W1, __hip_bfloat16* __restrict__ Wt1,
    const float* __restrict__ Wg, __hip_bfloat16* __restrict__ Wgt,
    const float* __restrict__ Wo, __hip_bfloat16* __restrict__ Wot,
    const float* __restrict__ x, __hip_bfloat16* __restrict__ xb) {
  const int bid = blockIdx.x;
  if (bid >= 9216) {  // x cast
    size_t e = (((size_t)(bid - 9216)) * 256 + threadIdx.x) * 4;
    float4 v = *(const float4*)(x + e);
    ushort4 o;
    o.x = f2bf(v.x); o.y = f2bf(v.y); o.z = f2bf(v.z); o.w = f2bf(v.w);
    *(ushort4*)((unsigned short*)xb + e) = o;
    return;
  }
  const float* in; __hip_bfloat16* out; int R, C, base;
  if (bid < 3072)      { in = W0; out = Wt0; R = 1024; C = 3072; base = 0; }
  else if (bid < 6144) { in = W1; out = Wt1; R = 1024; C = 3072; base = 3072; }
  else if (bid < 8192) { in = Wg; out = Wgt; R = 2048; C = 1024; base = 6144; }
  else                 { in = Wo; out = Wot; R = 1024; C = 1024; base = 8192; }
  const int local = bid - base, nbx = C / 32;
  const int bx = (local % nbx) * 32, by = (local / nbx) * 32;
  const int tx = threadIdx.x & 31, ty = threadIdx.x >> 5;
  __shared__ float t[32][33];
#pragma unroll
  for (int i = 0; i < 32; i += 8)
    t[ty + i][tx] = in[(size_t)(by + ty + i) * C + bx + tx];
  __syncthreads();
#pragma unroll
  for (int i = 0; i < 32; i += 8)
    out[(size_t)(bx + ty + i) * R + by + tx] = __float2bfloat16(t[tx][ty + i]);
}

// ------- bf16 MFMA GEMM, 128x128 tile, BK=32, double-buffered (R13) ---------
// EPI 0: out bf16 = acc+bias
// EPI 1: out bf16 = sigmoid(acc+bias)*bf16aux0 + bf16aux1 (aux stride 2048)
// EPI 2: out fp32 = acc+bias
template <int EPI>
__global__ __launch_bounds__(256) void gemm_bf16(
    const __hip_bfloat16* __restrict__ A, const __hip_bfloat16* __restrict__ Bt,
    const float* __restrict__ bias, void* __restrict__ outp,
    const __hip_bfloat16* __restrict__ aux0, const __hip_bfloat16* __restrict__ aux1,
    int M, int N, int K) {
  __shared__ __hip_bfloat16 As[2][128 * 32];
  __shared__ __hip_bfloat16 Bs[2][128 * 32];
  const int tid = threadIdx.x;
  const int lane = tid & 63, wid = tid >> 6;
  const int wr = wid >> 1, wc = wid & 1;
  const int lr = lane & 15, lk = (lane >> 4) * 8;
  const size_t brow = (size_t)blockIdx.y * 128, bcol = (size_t)blockIdx.x * 128;
  f32x4 acc[4][4] = {};
#pragma unroll
  for (int r = 0; r < 2; ++r) {
    int c = tid + r * 256;
    GLD16(A + (brow + (size_t)(c >> 2)) * K + (c & 3) * 8, As[0] + c * 8);
    GLD16(Bt + (bcol + (size_t)(c >> 2)) * K + (c & 3) * 8, Bs[0] + c * 8);
  }
  __syncthreads();
  int cur = 0;
  for (int k0 = 0; k0 < K; k0 += 32) {
    const int nxt = cur ^ 1;
    if (k0 + 32 < K) {
#pragma unroll
      for (int r = 0; r < 2; ++r) {
        int c = tid + r * 256;
        GLD16(A + (brow + (size_t)(c >> 2)) * K + k0 + 32 + (c & 3) * 8,
              As[nxt] + c * 8);
        GLD16(Bt + (bcol + (size_t)(c >> 2)) * K + k0 + 32 + (c & 3) * 8,
              Bs[nxt] + c * 8);
      }
    }
    bf16x8 a[4], b[4];
#pragma unroll
    for (int m = 0; m < 4; ++m)
      a[m] = *(const bf16x8*)(As[cur] + (wr * 64 + m * 16 + lr) * 32 + lk);
#pragma unroll
    for (int n = 0; n < 4; ++n)
      b[n] = *(const bf16x8*)(Bs[cur] + (wc * 64 + n * 16 + lr) * 32 + lk);
#pragma unroll
    for (int m = 0; m < 4; ++m)
#pragma unroll
      for (int n = 0; n < 4; ++n)
        acc[m][n] = __builtin_amdgcn_mfma_f32_16x16x32_bf16(a[m], b[n], acc[m][n], 0, 0, 0);
    __syncthreads();
    cur = nxt;
  }
  const int r0 = (lane >> 4) * 4, cn = lane & 15;
#pragma unroll
  for (int m = 0; m < 4; ++m)
#pragma unroll
    for (int n = 0; n < 4; ++n) {
      size_t col = bcol + wc * 64 + n * 16 + cn;
      float bv = bias[col];
#pragma unroll
      for (int j = 0; j < 4; ++j) {
        size_t row = brow + wr * 64 + m * 16 + r0 + j;
        float v = acc[m][n][j] + bv;
        if constexpr (EPI == 1) {
          float g = 1.0f / (1.0f + __expf(-v));
          float a0 = __bfloat162float(aux0[row * 2048 + col]);
          float a1 = __bfloat162float(aux1[row * 2048 + col]);
          ((__hip_bfloat16*)outp)[row * N + col] = __float2bfloat16(g * a0 + a1);
        } else if constexpr (EPI == 2) {
          ((float*)outp)[row * N + col] = v;
        } else {
          ((__hip_bfloat16*)outp)[row * N + col] = __float2bfloat16(v);
        }
      }
    }
}

// ------- causal flash attention V5e (R19 body + defer-max + resid fusion) ---
// R15/R17/R19-verified structure. T13 defer-max (THR=8, exact math). When
// ob_off==0 the epilogue also writes residb = bf16(x - pred) for its slice.
__global__ __launch_bounds__(256) void attn_kernel(
    const __hip_bfloat16* __restrict__ qkv,
    __hip_bfloat16* __restrict__ outb, int ob_off,
    const float* __restrict__ xg, __hip_bfloat16* __restrict__ residb) {
  const int b = blockIdx.z, h = blockIdx.y, qtp = blockIdx.x;
  const int qlo = qtp, qhi = 31 - qtp;
  const int q0lo = qlo * 64, q0hi = qhi * 64;
  __shared__ __hip_bfloat16 ks[2][64 * 64];
  __shared__ __hip_bfloat16 vts[2][64 * 64];  // V^T [dh][kv], swizzled
  __shared__ __hip_bfloat16 qps[8192];        // Q_hi|Q_lo staging -> ps_hi|ps_lo
  const int tid = threadIdx.x, lane = tid & 63, w = tid >> 6;
  const int lr = lane & 15, lg = lane >> 4;
  const int sw = lr & 7;
  const size_t rs = 3072;
  const __hip_bfloat16* qbh = qkv + ((size_t)b * 2048 + q0hi) * rs + h * 64;
  const __hip_bfloat16* qbl = qkv + ((size_t)b * 2048 + q0lo) * rs + h * 64;
  const __hip_bfloat16* kb = qkv + (size_t)b * 2048 * rs + 1024 + h * 64;
  const __hip_bfloat16* vb = qkv + (size_t)b * 2048 * rs + 2048 + h * 64;

  const int vrow2 = tid >> 3, vseg = tid & 7;
  float4 vr0, vr1;
#pragma unroll
  for (int r = 0; r < 2; ++r) {
    int c = tid + r * 256, row = c >> 3, p = c & 7;
    GLD16(qbh + (size_t)row * rs + (p ^ (row & 7)) * 8, qps + c * 8);
    GLD16(qbl + (size_t)row * rs + (p ^ (row & 7)) * 8, qps + 4096 + c * 8);
    GLD16(kb + (size_t)row * rs + (p ^ (row & 7)) * 8, ks[0] + c * 8);
  }
  vr0 = *(const float4*)(vb + (size_t)(2 * vrow2) * rs + vseg * 8);
  vr1 = *(const float4*)(vb + (size_t)(2 * vrow2 + 1) * rs + vseg * 8);
  __syncthreads();
  const int qrow = w * 16 + lr;
  const bf16x8 qh0 = *(const bf16x8*)(qps + qrow * 64 + ((lg) ^ (qrow & 7)) * 8);
  const bf16x8 qh1 = *(const bf16x8*)(qps + qrow * 64 + ((4 + lg) ^ (qrow & 7)) * 8);
  const bf16x8 ql0 = *(const bf16x8*)(qps + 4096 + qrow * 64 + ((lg) ^ (qrow & 7)) * 8);
  const bf16x8 ql1 = *(const bf16x8*)(qps + 4096 + qrow * 64 + ((4 + lg) ^ (qrow & 7)) * 8);
  {
    const unsigned short* u0 = (const unsigned short*)&vr0;
    const unsigned short* u1 = (const unsigned short*)&vr1;
#pragma unroll
    for (int i = 0; i < 8; ++i) {
      const int dh = vseg * 8 + i;
      const int phys = (vrow2 >> 2) ^ (dh & 7) ^ ((dh >> 3) & 7);
      unsigned int pk = (unsigned int)u0[i] | ((unsigned int)u1[i] << 16);
      *(unsigned int*)(vts[0] + dh * 64 + phys * 8 + 2 * (vrow2 & 3)) = pk;
    }
  }
  __syncthreads();  // Q frags in regs; qps now free for ps

  __hip_bfloat16* psh = qps + w * 1024;
  __hip_bfloat16* psl = qps + 4096 + w * 1024;
  float m_hi = -1e30f, l_hi = 0.f, m_lo = -1e30f, l_lo = 0.f;
  f32x4 o_hi[4] = {}, o_lo[4] = {};
  int cur = 0;

  auto process = [&](const bf16x8& qa0, const bf16x8& qa1, bool diag,
                     float& m_run, float& l_run, f32x4* o, __hip_bfloat16* psw) {
    f32x4 s4[4] = {};
    __builtin_amdgcn_s_setprio(1);
#pragma unroll
    for (int n = 0; n < 4; ++n) {
      const int kr = n * 16 + lr;
      bf16x8 k0f = *(const bf16x8*)(ks[cur] + kr * 64 + ((lg) ^ sw) * 8);
      bf16x8 k1f = *(const bf16x8*)(ks[cur] + kr * 64 + ((4 + lg) ^ sw) * 8);
      s4[n] = __builtin_amdgcn_mfma_f32_16x16x32_bf16(k0f, qa0, s4[n], 0, 0, 0);
      s4[n] = __builtin_amdgcn_mfma_f32_16x16x32_bf16(k1f, qa1, s4[n], 0, 0, 0);
    }
    __builtin_amdgcn_s_setprio(0);
    float p[4][4];
    float mloc = -1e30f;
#pragma unroll
    for (int n = 0; n < 4; ++n)
#pragma unroll
      for (int j = 0; j < 4; ++j) {
        float v = s4[n][j] * 0.125f;
        if (diag && (n * 16 + lg * 4 + j) > (w * 16 + lr)) v = -1e30f;
        p[n][j] = v;
        mloc = fmaxf(mloc, v);
      }
    mloc = fmaxf(mloc, __shfl_xor(mloc, 16));
    mloc = fmaxf(mloc, __shfl_xor(mloc, 32));
    // T13 defer-max: rescale only if some row's max grew past THR=8
    if (!__all(mloc - m_run <= 8.0f)) {
      const float mn = fmaxf(m_run, mloc);
      const float sc = __expf(m_run - mn);
      m_run = mn;
      l_run *= sc;
      float scb[4];
#pragma unroll
      for (int j = 0; j < 4; ++j) scb[j] = __shfl(sc, lg * 4 + j);
#pragma unroll
      for (int n = 0; n < 4; ++n)
#pragma unroll
        for (int j = 0; j < 4; ++j) o[n][j] *= scb[j];
    }
    float ls = 0.f;
#pragma unroll
    for (int n = 0; n < 4; ++n)
#pragma unroll
      for (int j = 0; j < 4; ++j) { p[n][j] = __expf(p[n][j] - m_run); ls += p[n][j]; }
    ls += __shfl_xor(ls, 16);
    ls += __shfl_xor(ls, 32);
    l_run += ls;
#pragma unroll
    for (int n = 0; n < 4; ++n)
#pragma unroll
      for (int j = 0; j < 4; ++j)
        psw[lr * 64 + ((n * 2 + (lg >> 1)) ^ sw) * 8 + (lg & 1) * 4 + j] =
            __float2bfloat16(p[n][j]);
    bf16x8 pa0 = *(const bf16x8*)(&psw[lr * 64 + ((lg) ^ sw) * 8]);
    bf16x8 pa1 = *(const bf16x8*)(&psw[lr * 64 + ((4 + lg) ^ sw) * 8]);
    __builtin_amdgcn_s_setprio(1);
#pragma unroll
    for (int n = 0; n < 4; ++n) {
      const int vdh = n * 16 + lr;
      const int swv = (vdh & 7) ^ ((vdh >> 3) & 7);
      bf16x8 v0f = *(const bf16x8*)(vts[cur] + vdh * 64 + ((lg) ^ swv) * 8);
      bf16x8 v1f = *(const bf16x8*)(vts[cur] + vdh * 64 + ((4 + lg) ^ swv) * 8);
      o[n] = __builtin_amdgcn_mfma_f32_16x16x32_bf16(pa0, v0f, o[n], 0, 0, 0);
      o[n] = __builtin_amdgcn_mfma_f32_16x16x32_bf16(pa1, v1f, o[n], 0, 0, 0);
    }
    __builtin_amdgcn_s_setprio(0);
  };

  for (int kvt = 0; kvt <= qhi; ++kvt) {
    const int nxt = cur ^ 1;
    const bool pf = (kvt < qhi);
    if (pf) {
      const int kv1 = (kvt + 1) * 64;
#pragma unroll
      for (int r = 0; r < 2; ++r) {
        int c = tid + r * 256, row = c >> 3, p = c & 7;
        GLD16(kb + (size_t)(kv1 + row) * rs + (p ^ (row & 7)) * 8, ks[nxt] + c * 8);
      }
      vr0 = *(const float4*)(vb + (size_t)(kv1 + 2 * vrow2) * rs + vseg * 8);
      vr1 = *(const float4*)(vb + (size_t)(kv1 + 2 * vrow2 + 1) * rs + vseg * 8);
    }
    process(qh0, qh1, kvt == qhi, m_hi, l_hi, o_hi, psh);
    if (kvt <= qlo) process(ql0, ql1, kvt == qlo, m_lo, l_lo, o_lo, psl);
    if (pf) {
      const unsigned short* u0 = (const unsigned short*)&vr0;
      const unsigned short* u1 = (const unsigned short*)&vr1;
#pragma unroll
      for (int i = 0; i < 8; ++i) {
        const int dh = vseg * 8 + i;
        const int phys = (vrow2 >> 2) ^ (dh & 7) ^ ((dh >> 3) & 7);
        unsigned int pk = (unsigned int)u0[i] | ((unsigned int)u1[i] << 16);
        *(unsigned int*)(vts[nxt] + dh * 64 + phys * 8 + 2 * (vrow2 & 3)) = pk;
      }
    }
    __syncthreads();
    cur = nxt;
  }
  const float linv_h = 1.0f / l_hi, linv_l = 1.0f / l_lo;
#pragma unroll
  for (int j = 0; j < 4; ++j) {
    const float lih = __shfl(linv_h, lg * 4 + j);
    const float lil = __shfl(linv_l, lg * 4 + j);
    size_t rowh = (size_t)b * 2048 + q0hi + w * 16 + lg * 4 + j;
    size_t rowl = (size_t)b * 2048 + q0lo + w * 16 + lg * 4 + j;
#pragma unroll
    for (int n = 0; n < 4; ++n) {
      float vh = o_hi[n][j] * lih, vl = o_lo[n][j] * lil;
      const int col = h * 64 + n * 16 + lr;
      outb[rowh * 2048 + ob_off + col] = __float2bfloat16(vh);
      outb[rowl * 2048 + ob_off + col] = __float2bfloat16(vl);
      if (ob_off == 0) {  // fused resid: residb = bf16(x - pred)
        residb[rowh * 1024 + col] = __float2bfloat16(xg[rowh * 1024 + col] - vh);
        residb[rowl * 1024 + col] = __float2bfloat16(xg[rowl * 1024 + col] - vl);
      }
    }
  }
}

extern "C" void kernel_launch(void* const* d_in, const int* in_sizes, int n_in,
                              void* d_out, int out_size, void* d_ws, size_t ws_size,
                              hipStream_t stream) {
  const float* x     = (const float*)d_in[0];
  const float* Wqkv0 = (const float*)d_in[1];
  const float* bqkv0 = (const float*)d_in[2];
  const float* Wqkv1 = (const float*)d_in[3];
  const float* bqkv1 = (const float*)d_in[4];
  const float* Wg    = (const float*)d_in[5];
  const float* bg    = (const float*)d_in[6];
  const float* Wo    = (const float*)d_in[7];
  const float* bo    = (const float*)d_in[8];
  float* out = (float*)d_out;

  char* ws = (char*)d_ws;
  __hip_bfloat16* xb   = (__hip_bfloat16*)(ws);              // 8 MB (x_bf16 -> residb -> preout)
  __hip_bfloat16* qkv  = (__hip_bfloat16*)(ws + 8388608);    // 24 MB (qkv0 then qkv1)
  __hip_bfloat16* catb = (__hip_bfloat16*)(ws + 67108864);   // 16 MB [pred | corr] bf16
  __hip_bfloat16* Wt0  = (__hip_bfloat16*)(ws + 83886080);   // 6 MB
  __hip_bfloat16* Wt1  = (__hip_bfloat16*)(ws + 90177536);   // 6 MB
  __hip_bfloat16* Wgt  = (__hip_bfloat16*)(ws + 96468992);   // 4 MB
  __hip_bfloat16* Wot  = (__hip_bfloat16*)(ws + 100663296);  // 2 MB

  // all prep in one dispatch
  prep_batch<<<13312, 256, 0, stream>>>(Wqkv0, Wt0, Wqkv1, Wt1, Wg, Wgt,
                                        Wo, Wot, x, xb);

  // qkv0 = x @ Wqkv0 + b  (128^2 dbuf, verified)
  gemm_bf16<0><<<dim3(24, 32), 256, 0, stream>>>(xb, Wt0, bqkv0, (void*)qkv,
                                                 nullptr, nullptr, 4096, 3072, 1024);
  // attn0: pred -> catb[:, :1024]; fused residb = bf16(x - pred) -> xb
  attn_kernel<<<dim3(16, 16, 2), 256, 0, stream>>>(qkv, catb, 0, x, xb);
  // qkv1 = (x - pred) @ Wqkv1 + b
  gemm_bf16<0><<<dim3(24, 32), 256, 0, stream>>>(xb, Wt1, bqkv1, (void*)qkv,
                                                 nullptr, nullptr, 4096, 3072, 1024);
  // attn1: corr -> catb[:, 1024:]
  attn_kernel<<<dim3(16, 16, 2), 256, 0, stream>>>(qkv, catb, 1024, nullptr, nullptr);
  // preout = sigmoid(cat @ Wg + bg) * corr + pred   (into xb, aux from catb)
  gemm_bf16<1><<<dim3(8, 32), 256, 0, stream>>>(catb, Wgt, bg, (void*)xb,
                                                catb + 1024, catb, 4096, 1024, 2048);
  // out = preout @ Wo + bo (fp32)
  gemm_bf16<2><<<dim3(8, 32), 256, 0, stream>>>(xb, Wot, bo, (void*)out,
                                                nullptr, nullptr, 4096, 1024, 1024);
}

// Round 24
// 283.112 us; speedup vs baseline: 1.0774x; 1.0138x over previous
//
#include <hip/hip_runtime.h>
#include <hip/hip_bf16.h>

// BoostedCausalAttention: bf16 MFMA pipeline
// B=2 T=2048 D=1024 H=16 DH=64, fp32 in/out, bf16 internal compute.
// R6 589 -> R8 swizzle 475 -> R9 pairing 352.9 -> R15 swapped-QK 309.3 ->
// R17 302.2 -> R19 297.4 -> R21 (verified) 287.0 (batched prep + fused
// resid + T13; attn 72.9 each, GEMMs ~650 TF).
// R22: (1) T1 XCD swizzle on all 4 GEMMs (1-D grid, swz=(bid&7)*cpx+bid>>3,
//   x-fastest decode: each XCD owns 4 by-rows -> 1MB A-slice fits 4MB L2,
//   B streams via L3). Grids 768/768/256/256 all %8==0 (bijective).
//   (2) attn0 fused-resid reads xb (bf16) not x (fp32): -4MB FETCH;
//   same-thread read-before-write on xb is race-free.
// R23/R24: identical resubmits (infra UnresponsiveContainer twice; audits
//   clean: swizzle bijective, L2-fit, race-free resid, gate aux mapping).

typedef __bf16 bf16x8 __attribute__((ext_vector_type(8)));
typedef float f32x4 __attribute__((ext_vector_type(4)));

__device__ __forceinline__ unsigned short f2bf(float f) {
  union { __hip_bfloat16 h; unsigned short u; } cv;
  cv.h = __float2bfloat16(f);
  return cv.u;
}

#define GLD16(gp, lp) __builtin_amdgcn_global_load_lds(                      \
    (const __attribute__((address_space(1))) void*)(gp),                     \
    (__attribute__((address_space(3))) void*)(lp), 16, 0, 0)

// ---- batched prep: 4x transpose_cast + x cast in one dispatch --------------
__global__ __launch_bounds__(256) void prep_batch(
    const float* __restrict__ W0, __hip_bfloat16* __restrict__ Wt0,
    const float* __restrict__ W1, __hip_bfloat16* __restrict__ Wt1,
    const float* __restrict__ Wg, __hip_bfloat16* __restrict__ Wgt,
    const float* __restrict__ Wo, __hip_bfloat16* __restrict__ Wot,
    const float* __restrict__ x, __hip_bfloat16* __restrict__ xb) {
  const int bid = blockIdx.x;
  if (bid >= 9216) {  // x cast
    size_t e = (((size_t)(bid - 9216)) * 256 + threadIdx.x) * 4;
    float4 v = *(const float4*)(x + e);
    ushort4 o;
    o.x = f2bf(v.x); o.y = f2bf(v.y); o.z = f2bf(v.z); o.w = f2bf(v.w);
    *(ushort4*)((unsigned short*)xb + e) = o;
    return;
  }
  const float* in; __hip_bfloat16* out; int R, C, base;
  if (bid < 3072)      { in = W0; out = Wt0; R = 1024; C = 3072; base = 0; }
  else if (bid < 6144) { in = W1; out = Wt1; R = 1024; C = 3072; base = 3072; }
  else if (bid < 8192) { in = Wg; out = Wgt; R = 2048; C = 1024; base = 6144; }
  else                 { in = Wo; out = Wot; R = 1024; C = 1024; base = 8192; }
  const int local = bid - base, nbx = C / 32;
  const int bx = (local % nbx) * 32, by = (local / nbx) * 32;
  const int tx = threadIdx.x & 31, ty = threadIdx.x >> 5;
  __shared__ float t[32][33];
#pragma unroll
  for (int i = 0; i < 32; i += 8)
    t[ty + i][tx] = in[(size_t)(by + ty + i) * C + bx + tx];
  __syncthreads();
#pragma unroll
  for (int i = 0; i < 32; i += 8)
    out[(size_t)(bx + ty + i) * R + by + tx] = __float2bfloat16(t[tx][ty + i]);
}

// ------- bf16 MFMA GEMM, 128x128 tile, BK=32, dbuf, T1 XCD swizzle ----------
// 1-D grid (must be %8==0). swz=(bid&7)*cpx+(bid>>3); bx=swz%nbx (x-fastest).
// EPI 0: bf16 acc+bias; EPI 1: bf16 sigmoid(acc+bias)*aux0+aux1 (aux bf16,
// stride 2048); EPI 2: fp32 acc+bias.
template <int EPI>
__global__ __launch_bounds__(256) void gemm_bf16(
    const __hip_bfloat16* __restrict__ A, const __hip_bfloat16* __restrict__ Bt,
    const float* __restrict__ bias, void* __restrict__ outp,
    const __hip_bfloat16* __restrict__ aux0, const __hip_bfloat16* __restrict__ aux1,
    int M, int N, int K) {
  __shared__ __hip_bfloat16 As[2][128 * 32];
  __shared__ __hip_bfloat16 Bs[2][128 * 32];
  const int tid = threadIdx.x;
  const int lane = tid & 63, wid = tid >> 6;
  const int wr = wid >> 1, wc = wid & 1;
  const int lr = lane & 15, lk = (lane >> 4) * 8;
  const int nbx = N >> 7;
  const int cpx = gridDim.x >> 3;
  const int swz = (blockIdx.x & 7) * cpx + (blockIdx.x >> 3);
  const size_t bcol = (size_t)(swz % nbx) * 128;
  const size_t brow = (size_t)(swz / nbx) * 128;
  f32x4 acc[4][4] = {};
#pragma unroll
  for (int r = 0; r < 2; ++r) {
    int c = tid + r * 256;
    GLD16(A + (brow + (size_t)(c >> 2)) * K + (c & 3) * 8, As[0] + c * 8);
    GLD16(Bt + (bcol + (size_t)(c >> 2)) * K + (c & 3) * 8, Bs[0] + c * 8);
  }
  __syncthreads();
  int cur = 0;
  for (int k0 = 0; k0 < K; k0 += 32) {
    const int nxt = cur ^ 1;
    if (k0 + 32 < K) {
#pragma unroll
      for (int r = 0; r < 2; ++r) {
        int c = tid + r * 256;
        GLD16(A + (brow + (size_t)(c >> 2)) * K + k0 + 32 + (c & 3) * 8,
              As[nxt] + c * 8);
        GLD16(Bt + (bcol + (size_t)(c >> 2)) * K + k0 + 32 + (c & 3) * 8,
              Bs[nxt] + c * 8);
      }
    }
    bf16x8 a[4], b[4];
#pragma unroll
    for (int m = 0; m < 4; ++m)
      a[m] = *(const bf16x8*)(As[cur] + (wr * 64 + m * 16 + lr) * 32 + lk);
#pragma unroll
    for (int n = 0; n < 4; ++n)
      b[n] = *(const bf16x8*)(Bs[cur] + (wc * 64 + n * 16 + lr) * 32 + lk);
#pragma unroll
    for (int m = 0; m < 4; ++m)
#pragma unroll
      for (int n = 0; n < 4; ++n)
        acc[m][n] = __builtin_amdgcn_mfma_f32_16x16x32_bf16(a[m], b[n], acc[m][n], 0, 0, 0);
    __syncthreads();
    cur = nxt;
  }
  const int r0 = (lane >> 4) * 4, cn = lane & 15;
#pragma unroll
  for (int m = 0; m < 4; ++m)
#pragma unroll
    for (int n = 0; n < 4; ++n) {
      size_t col = bcol + wc * 64 + n * 16 + cn;
      float bv = bias[col];
#pragma unroll
      for (int j = 0; j < 4; ++j) {
        size_t row = brow + wr * 64 + m * 16 + r0 + j;
        float v = acc[m][n][j] + bv;
        if constexpr (EPI == 1) {
          float g = 1.0f / (1.0f + __expf(-v));
          float a0 = __bfloat162float(aux0[row * 2048 + col]);
          float a1 = __bfloat162float(aux1[row * 2048 + col]);
          ((__hip_bfloat16*)outp)[row * N + col] = __float2bfloat16(g * a0 + a1);
        } else if constexpr (EPI == 2) {
          ((float*)outp)[row * N + col] = v;
        } else {
          ((__hip_bfloat16*)outp)[row * N + col] = __float2bfloat16(v);
        }
      }
    }
}

// ------- causal flash attention V5e (R21 body; resid reads xb bf16) ---------
__global__ __launch_bounds__(256) void attn_kernel(
    const __hip_bfloat16* __restrict__ qkv,
    __hip_bfloat16* __restrict__ outb, int ob_off,
    const __hip_bfloat16* __restrict__ xg, __hip_bfloat16* __restrict__ residb) {
  const int b = blockIdx.z, h = blockIdx.y, qtp = blockIdx.x;
  const int qlo = qtp, qhi = 31 - qtp;
  const int q0lo = qlo * 64, q0hi = qhi * 64;
  __shared__ __hip_bfloat16 ks[2][64 * 64];
  __shared__ __hip_bfloat16 vts[2][64 * 64];  // V^T [dh][kv], swizzled
  __shared__ __hip_bfloat16 qps[8192];        // Q_hi|Q_lo staging -> ps_hi|ps_lo
  const int tid = threadIdx.x, lane = tid & 63, w = tid >> 6;
  const int lr = lane & 15, lg = lane >> 4;
  const int sw = lr & 7;
  const size_t rs = 3072;
  const __hip_bfloat16* qbh = qkv + ((size_t)b * 2048 + q0hi) * rs + h * 64;
  const __hip_bfloat16* qbl = qkv + ((size_t)b * 2048 + q0lo) * rs + h * 64;
  const __hip_bfloat16* kb = qkv + (size_t)b * 2048 * rs + 1024 + h * 64;
  const __hip_bfloat16* vb = qkv + (size_t)b * 2048 * rs + 2048 + h * 64;

  const int vrow2 = tid >> 3, vseg = tid & 7;
  float4 vr0, vr1;
#pragma unroll
  for (int r = 0; r < 2; ++r) {
    int c = tid + r * 256, row = c >> 3, p = c & 7;
    GLD16(qbh + (size_t)row * rs + (p ^ (row & 7)) * 8, qps + c * 8);
    GLD16(qbl + (size_t)row * rs + (p ^ (row & 7)) * 8, qps + 4096 + c * 8);
    GLD16(kb + (size_t)row * rs + (p ^ (row & 7)) * 8, ks[0] + c * 8);
  }
  vr0 = *(const float4*)(vb + (size_t)(2 * vrow2) * rs + vseg * 8);
  vr1 = *(const float4*)(vb + (size_t)(2 * vrow2 + 1) * rs + vseg * 8);
  __syncthreads();
  const int qrow = w * 16 + lr;
  const bf16x8 qh0 = *(const bf16x8*)(qps + qrow * 64 + ((lg) ^ (qrow & 7)) * 8);
  const bf16x8 qh1 = *(const bf16x8*)(qps + qrow * 64 + ((4 + lg) ^ (qrow & 7)) * 8);
  const bf16x8 ql0 = *(const bf16x8*)(qps + 4096 + qrow * 64 + ((lg) ^ (qrow & 7)) * 8);
  const bf16x8 ql1 = *(const bf16x8*)(qps + 4096 + qrow * 64 + ((4 + lg) ^ (qrow & 7)) * 8);
  {
    const unsigned short* u0 = (const unsigned short*)&vr0;
    const unsigned short* u1 = (const unsigned short*)&vr1;
#pragma unroll
    for (int i = 0; i < 8; ++i) {
      const int dh = vseg * 8 + i;
      const int phys = (vrow2 >> 2) ^ (dh & 7) ^ ((dh >> 3) & 7);
      unsigned int pk = (unsigned int)u0[i] | ((unsigned int)u1[i] << 16);
      *(unsigned int*)(vts[0] + dh * 64 + phys * 8 + 2 * (vrow2 & 3)) = pk;
    }
  }
  __syncthreads();  // Q frags in regs; qps now free for ps

  __hip_bfloat16* psh = qps + w * 1024;
  __hip_bfloat16* psl = qps + 4096 + w * 1024;
  float m_hi = -1e30f, l_hi = 0.f, m_lo = -1e30f, l_lo = 0.f;
  f32x4 o_hi[4] = {}, o_lo[4] = {};
  int cur = 0;

  auto process = [&](const bf16x8& qa0, const bf16x8& qa1, bool diag,
                     float& m_run, float& l_run, f32x4* o, __hip_bfloat16* psw) {
    f32x4 s4[4] = {};
    __builtin_amdgcn_s_setprio(1);
#pragma unroll
    for (int n = 0; n < 4; ++n) {
      const int kr = n * 16 + lr;
      bf16x8 k0f = *(const bf16x8*)(ks[cur] + kr * 64 + ((lg) ^ sw) * 8);
      bf16x8 k1f = *(const bf16x8*)(ks[cur] + kr * 64 + ((4 + lg) ^ sw) * 8);
      s4[n] = __builtin_amdgcn_mfma_f32_16x16x32_bf16(k0f, qa0, s4[n], 0, 0, 0);
      s4[n] = __builtin_amdgcn_mfma_f32_16x16x32_bf16(k1f, qa1, s4[n], 0, 0, 0);
    }
    __builtin_amdgcn_s_setprio(0);
    float p[4][4];
    float mloc = -1e30f;
#pragma unroll
    for (int n = 0; n < 4; ++n)
#pragma unroll
      for (int j = 0; j < 4; ++j) {
        float v = s4[n][j] * 0.125f;
        if (diag && (n * 16 + lg * 4 + j) > (w * 16 + lr)) v = -1e30f;
        p[n][j] = v;
        mloc = fmaxf(mloc, v);
      }
    mloc = fmaxf(mloc, __shfl_xor(mloc, 16));
    mloc = fmaxf(mloc, __shfl_xor(mloc, 32));
    if (!__all(mloc - m_run <= 8.0f)) {  // T13 defer-max
      const float mn = fmaxf(m_run, mloc);
      const float sc = __expf(m_run - mn);
      m_run = mn;
      l_run *= sc;
      float scb[4];
#pragma unroll
      for (int j = 0; j < 4; ++j) scb[j] = __shfl(sc, lg * 4 + j);
#pragma unroll
      for (int n = 0; n < 4; ++n)
#pragma unroll
        for (int j = 0; j < 4; ++j) o[n][j] *= scb[j];
    }
    float ls = 0.f;
#pragma unroll
    for (int n = 0; n < 4; ++n)
#pragma unroll
      for (int j = 0; j < 4; ++j) { p[n][j] = __expf(p[n][j] - m_run); ls += p[n][j]; }
    ls += __shfl_xor(ls, 16);
    ls += __shfl_xor(ls, 32);
    l_run += ls;
#pragma unroll
    for (int n = 0; n < 4; ++n)
#pragma unroll
      for (int j = 0; j < 4; ++j)
        psw[lr * 64 + ((n * 2 + (lg >> 1)) ^ sw) * 8 + (lg & 1) * 4 + j] =
            __float2bfloat16(p[n][j]);
    bf16x8 pa0 = *(const bf16x8*)(&psw[lr * 64 + ((lg) ^ sw) * 8]);
    bf16x8 pa1 = *(const bf16x8*)(&psw[lr * 64 + ((4 + lg) ^ sw) * 8]);
    __builtin_amdgcn_s_setprio(1);
#pragma unroll
    for (int n = 0; n < 4; ++n) {
      const int vdh = n * 16 + lr;
      const int swv = (vdh & 7) ^ ((vdh >> 3) & 7);
      bf16x8 v0f = *(const bf16x8*)(vts[cur] + vdh * 64 + ((lg) ^ swv) * 8);
      bf16x8 v1f = *(const bf16x8*)(vts[cur] + vdh * 64 + ((4 + lg) ^ swv) * 8);
      o[n] = __builtin_amdgcn_mfma_f32_16x16x32_bf16(pa0, v0f, o[n], 0, 0, 0);
      o[n] = __builtin_amdgcn_mfma_f32_16x16x32_bf16(pa1, v1f, o[n], 0, 0, 0);
    }
    __builtin_amdgcn_s_setprio(0);
  };

  for (int kvt = 0; kvt <= qhi; ++kvt) {
    const int nxt = cur ^ 1;
    const bool pf = (kvt < qhi);
    if (pf) {
      const int kv1 = (kvt + 1) * 64;
#pragma unroll
      for (int r = 0; r < 2; ++r) {
        int c = tid + r * 256, row = c >> 3, p = c & 7;
        GLD16(kb + (size_t)(kv1 + row) * rs + (p ^ (row & 7)) * 8, ks[nxt] + c * 8);
      }
      vr0 = *(const float4*)(vb + (size_t)(kv1 + 2 * vrow2) * rs + vseg * 8);
      vr1 = *(const float4*)(vb + (size_t)(kv1 + 2 * vrow2 + 1) * rs + vseg * 8);
    }
    process(qh0, qh1, kvt == qhi, m_hi, l_hi, o_hi, psh);
    if (kvt <= qlo) process(ql0, ql1, kvt == qlo, m_lo, l_lo, o_lo, psl);
    if (pf) {
      const unsigned short* u0 = (const unsigned short*)&vr0;
      const unsigned short* u1 = (const unsigned short*)&vr1;
#pragma unroll
      for (int i = 0; i < 8; ++i) {
        const int dh = vseg * 8 + i;
        const int phys = (vrow2 >> 2) ^ (dh & 7) ^ ((dh >> 3) & 7);
        unsigned int pk = (unsigned int)u0[i] | ((unsigned int)u1[i] << 16);
        *(unsigned int*)(vts[nxt] + dh * 64 + phys * 8 + 2 * (vrow2 & 3)) = pk;
      }
    }
    __syncthreads();
    cur = nxt;
  }
  const float linv_h = 1.0f / l_hi, linv_l = 1.0f / l_lo;
#pragma unroll
  for (int j = 0; j < 4; ++j) {
    const float lih = __shfl(linv_h, lg * 4 + j);
    const float lil = __shfl(linv_l, lg * 4 + j);
    size_t rowh = (size_t)b * 2048 + q0hi + w * 16 + lg * 4 + j;
    size_t rowl = (size_t)b * 2048 + q0lo + w * 16 + lg * 4 + j;
#pragma unroll
    for (int n = 0; n < 4; ++n) {
      float vh = o_hi[n][j] * lih, vl = o_lo[n][j] * lil;
      const int col = h * 64 + n * 16 + lr;
      outb[rowh * 2048 + ob_off + col] = __float2bfloat16(vh);
      outb[rowl * 2048 + ob_off + col] = __float2bfloat16(vl);
      if (ob_off == 0) {  // fused resid: residb = bf16(x - pred), x from xb
        float xh = __bfloat162float(xg[rowh * 1024 + col]);
        float xl = __bfloat162float(xg[rowl * 1024 + col]);
        residb[rowh * 1024 + col] = __float2bfloat16(xh - vh);
        residb[rowl * 1024 + col] = __float2bfloat16(xl - vl);
      }
    }
  }
}

extern "C" void kernel_launch(void* const* d_in, const int* in_sizes, int n_in,
                              void* d_out, int out_size, void* d_ws, size_t ws_size,
                              hipStream_t stream) {
  const float* x     = (const float*)d_in[0];
  const float* Wqkv0 = (const float*)d_in[1];
  const float* bqkv0 = (const float*)d_in[2];
  const float* Wqkv1 = (const float*)d_in[3];
  const float* bqkv1 = (const float*)d_in[4];
  const float* Wg    = (const float*)d_in[5];
  const float* bg    = (const float*)d_in[6];
  const float* Wo    = (const float*)d_in[7];
  const float* bo    = (const float*)d_in[8];
  float* out = (float*)d_out;

  char* ws = (char*)d_ws;
  __hip_bfloat16* xb   = (__hip_bfloat16*)(ws);              // 8 MB (x_bf16 -> residb -> preout)
  __hip_bfloat16* qkv  = (__hip_bfloat16*)(ws + 8388608);    // 24 MB (qkv0 then qkv1)
  __hip_bfloat16* catb = (__hip_bfloat16*)(ws + 67108864);   // 16 MB [pred | corr] bf16
  __hip_bfloat16* Wt0  = (__hip_bfloat16*)(ws + 83886080);   // 6 MB
  __hip_bfloat16* Wt1  = (__hip_bfloat16*)(ws + 90177536);   // 6 MB
  __hip_bfloat16* Wgt  = (__hip_bfloat16*)(ws + 96468992);   // 4 MB
  __hip_bfloat16* Wot  = (__hip_bfloat16*)(ws + 100663296);  // 2 MB

  // all prep in one dispatch
  prep_batch<<<13312, 256, 0, stream>>>(Wqkv0, Wt0, Wqkv1, Wt1, Wg, Wgt,
                                        Wo, Wot, x, xb);

  // qkv0 = x @ Wqkv0 + b  (128^2 dbuf + T1, 768 blocks)
  gemm_bf16<0><<<768, 256, 0, stream>>>(xb, Wt0, bqkv0, (void*)qkv,
                                        nullptr, nullptr, 4096, 3072, 1024);
  // attn0: pred -> catb[:, :1024]; fused residb = bf16(xb - pred) -> xb
  attn_kernel<<<dim3(16, 16, 2), 256, 0, stream>>>(qkv, catb, 0, xb, xb);
  // qkv1 = (x - pred) @ Wqkv1 + b
  gemm_bf16<0><<<768, 256, 0, stream>>>(xb, Wt1, bqkv1, (void*)qkv,
                                        nullptr, nullptr, 4096, 3072, 1024);
  // attn1: corr -> catb[:, 1024:]
  attn_kernel<<<dim3(16, 16, 2), 256, 0, stream>>>(qkv, catb, 1024, nullptr, nullptr);
  // preout = sigmoid(cat @ Wg + bg) * corr + pred   (into xb, aux from catb)
  gemm_bf16<1><<<256, 256, 0, stream>>>(catb, Wgt, bg, (void*)xb,
                                        catb + 1024, catb, 4096, 1024, 2048);
  // out = preout @ Wo + bo (fp32)
  gemm_bf16<2><<<256, 256, 0, stream>>>(xb, Wot, bo, (void*)out,
                                        nullptr, nullptr, 4096, 1024, 1024);
}